// Round 6
// baseline (256.222 us; speedup 1.0000x reference)
//
#include <hip/hip_runtime.h>
#include <hip/hip_bf16.h>
#include <stdint.h>

#define NV   65536   // active voxels
#define KOFF 27      // kernel offsets
#define CIN  128
#define COUT 128
#define NSEC (NV + 128)   // nbr per-offset stride (16B-aligned; slot NV = dummy)

typedef __bf16 bf16x8 __attribute__((ext_vector_type(8)));
typedef float  f32x4  __attribute__((ext_vector_type(4)));

__device__ __forceinline__ void async_copy16(void* lds, const void* g) {
    __builtin_amdgcn_global_load_lds(
        (const __attribute__((address_space(1))) void*)g,
        (__attribute__((address_space(3))) void*)lds,
        16, 0, 0);
}

// ---- fused prep kernel --------------------------------------------------
// JOB_S back to identity scatter (plain row order): nbr[k][out] = in.
// The producer wave reads rows 4l..4l+3 per lane as one int4.
#define JOB_A_BLOCKS 4097
#define JOB_B_BLOCKS 216    // 27*4*4*2*64 chunks / 256
#define JOB_S_BLOCKS 1728   // 27*65536/4/256

__global__ void k_prep_all(const float* __restrict__ f,
                           uint4* __restrict__ fb4,
                           const float* __restrict__ w,
                           uint4* __restrict__ wfrag4,
                           const int4* __restrict__ in4,
                           const int4* __restrict__ out4,
                           int* __restrict__ nbr) {
    const int b = blockIdx.x;
    const int t = threadIdx.x;
    if (b < JOB_A_BLOCKS) {
        int i = b * 256 + t;
        int total8  = (NV + 1) * CIN / 8;
        int nvalid8 = NV * CIN / 8;
        if (i >= total8) return;
        union { uint4 u; __hip_bfloat16 h[8]; } p;
        if (i < nvalid8) {
            const float4* f4 = (const float4*)f;
            float4 a = f4[i * 2];
            float4 c = f4[i * 2 + 1];
            p.h[0] = __float2bfloat16(a.x);
            p.h[1] = __float2bfloat16(a.y);
            p.h[2] = __float2bfloat16(a.z);
            p.h[3] = __float2bfloat16(a.w);
            p.h[4] = __float2bfloat16(c.x);
            p.h[5] = __float2bfloat16(c.y);
            p.h[6] = __float2bfloat16(c.z);
            p.h[7] = __float2bfloat16(c.w);
        } else {
            p.u = make_uint4(0, 0, 0, 0);
        }
        fb4[i] = p.u;
    } else if (b < JOB_A_BLOCKS + JOB_B_BLOCKS) {
        int c    = (b - JOB_A_BLOCKS) * 256 + t;
        int lane = c & 63;
        int nt   = (c >> 6) & 1;
        int ks   = (c >> 7) & 3;
        int wv   = (c >> 9) & 3;
        int k    = c >> 11;
        int cout = wv * 32 + nt * 16 + (lane & 15);
        int cin0 = ks * 32 + (lane >> 4) * 8;
        const float* wk = w + k * 16384;
        union { uint4 u; __hip_bfloat16 h[8]; } p;
        #pragma unroll
        for (int j = 0; j < 8; ++j)
            p.h[j] = __float2bfloat16(wk[(cin0 + j) * 128 + cout]);
        wfrag4[c] = p.u;
    } else {
        int i = (b - JOB_A_BLOCKS - JOB_B_BLOCKS) * 256 + t;
        int k = i >> 14;
        int4 ii = in4[i];
        int4 oo = out4[i];
        int* nb = nbr + (size_t)k * NSEC;
        nb[oo.x] = ii.x;
        nb[oo.y] = ii.y;
        nb[oo.z] = ii.z;
        nb[oo.w] = ii.w;
    }
}

// ---- main gather-GEMM kernel -------------------------------------------
// PRODUCER-CONSUMER wave specialization. 320 threads:
//   waves 0-3 (consumers): R4's proven decomposition — each computes all
//     128 rows x its 32-col slice. Pure ds_read+MFMA + own B prefetch.
//     NO staging, NO nbr loads, NO vmcnt asm -> MFMA issue never blocked
//     behind the gather stream.
//   wave 4 (producer): ALL A-staging. Per offset: 1 int4 nbr load (rows
//     4l..4l+3 per lane, broadcast via readlane), 32 global_load_lds,
//     vmcnt(0), barrier. Gather latency/service overlaps consumers' MFMA
//     on the previous buffer by construction.
// One s_barrier per offset (27 total, equal count both roles).
__global__ __launch_bounds__(320, 2)
void sp_conv_main(const __hip_bfloat16* __restrict__ feats,
                  const uint4* __restrict__ wfrag,
                  const int* __restrict__ nbrp,
                  const float* __restrict__ bias,
                  float* __restrict__ out) {
    __shared__ unsigned char smem[65536];   // two 32 KB A buffers

    const int t   = threadIdx.x;
    const int bid = blockIdx.x;
    // XCD swizzle: consecutive 64-tile ranges per XCD (512 % 8 == 0, bijective)
    const int tile0 = ((bid & 7) * 64 + (bid >> 3)) * 128;

    const int w    = t >> 6;       // 0..4
    const int lane = t & 63;
    const int lr   = lane & 15;
    const int quad = lane >> 4;

    const unsigned char* featsB = (const unsigned char*)feats;

    if (w == 4) {
        // ================= producer wave =================
        auto NBRLOAD = [&](int k) {
            int4 v = make_int4(NV, NV, NV, NV);
            if (lane < 32)   // lanes 0..31 cover rows 4l..4l+3
                v = *(const int4*)(nbrp + (size_t)k * NSEC + tile0 + lane * 4);
            return v;
        };
        // stage 32 KB: instr j covers rows j*4+quad, phys chunk lane&15
        // holding global chunk (lane&15)^(r&15)  (consumer-side XOR map)
        auto PSTAGE = [&](int sb, int4 nv) {
            #pragma unroll
            for (int j = 0; j < 32; ++j) {
                unsigned r0 = min((unsigned)__builtin_amdgcn_readlane(nv.x, j), (unsigned)NV);
                unsigned r1 = min((unsigned)__builtin_amdgcn_readlane(nv.y, j), (unsigned)NV);
                unsigned r2 = min((unsigned)__builtin_amdgcn_readlane(nv.z, j), (unsigned)NV);
                unsigned r3 = min((unsigned)__builtin_amdgcn_readlane(nv.w, j), (unsigned)NV);
                unsigned ar = quad == 0 ? r0 : quad == 1 ? r1 : quad == 2 ? r2 : r3;
                unsigned chunk = (unsigned)(lane & 15) ^ ((unsigned)(j & 3) * 4 + (unsigned)quad);
                async_copy16(smem + sb + j * 1024 + lane * 16,
                             featsB + (size_t)ar * 256 + chunk * 16);
            }
        };

        int4 nvC = NBRLOAD(0);
        int4 nvN = NBRLOAD(1);
        PSTAGE(0, nvC);                       // stage offset 0 -> buf0
        asm volatile("s_waitcnt vmcnt(0)" ::: "memory");
        __builtin_amdgcn_s_barrier();         // barrier #1 (prologue)
        nvC = nvN;
        #pragma unroll 1
        for (int k = 0; k < KOFF - 1; ++k) {  // 26 iters, barriers #2..#27
            nvN = NBRLOAD(min(k + 2, KOFF - 1));       // rows for offset k+2
            PSTAGE(((k + 1) & 1) * 32768, nvC);        // stage offset k+1
            asm volatile("s_waitcnt vmcnt(0)" ::: "memory");
            __builtin_amdgcn_s_barrier();
            nvC = nvN;
        }
        return;   // exited waves don't block remaining barriers (none left)
    }

    // ================= consumer waves 0..3 =================
    f32x4 acc[8][2] = {};  // 64 VGPRs
    uint4 bA[4][2], bB[4][2];

    auto BLOAD = [&](const uint4* wfk, uint4 (&b)[4][2]) {
        #pragma unroll
        for (int ks = 0; ks < 4; ++ks)
            #pragma unroll
            for (int nt = 0; nt < 2; ++nt)
                b[ks][nt] = wfk[ks * 128 + nt * 64];
    };
    auto AFLOAD = [&](int rb, int ks, bf16x8 (&af)[8]) {
        #pragma unroll
        for (int mt = 0; mt < 8; ++mt)
            af[mt] = *(const bf16x8*)(smem + rb + (mt * 16 + lr) * 256 +
                                      (((ks * 4 + quad) ^ lr) * 16));
    };
    auto MFMA16 = [&](bf16x8 (&af)[8], uint4 (&b)[2]) {
        #pragma unroll
        for (int mt = 0; mt < 8; ++mt)
            #pragma unroll
            for (int nt = 0; nt < 2; ++nt)
                acc[mt][nt] = __builtin_amdgcn_mfma_f32_16x16x32_bf16(
                    af[mt], *(const bf16x8*)&b[nt], acc[mt][nt], 0, 0, 0);
    };
    auto COMPUTE = [&](int rb, uint4 (&buse)[4][2]) {
        #pragma unroll
        for (int ks = 0; ks < 4; ++ks) {
            bf16x8 af[8];
            AFLOAD(rb, ks, af);
            MFMA16(af, buse[ks]);
        }
    };

    BLOAD(wfrag + w * 512 + lane, bA);        // B(0)
    __builtin_amdgcn_s_barrier();             // barrier #1: A0 staged

    #pragma unroll 1
    for (int kk = 0; kk < KOFF - 1; kk += 2) {
        // offset kk (buf0, bA); prefetch B(kk+1)
        BLOAD(wfrag + (kk + 1) * 2048 + w * 512 + lane, bB);
        COMPUTE(0, bA);
        __builtin_amdgcn_s_barrier();
        // offset kk+1 (buf1, bB); prefetch B(kk+2)  [kk+2 <= 26 always]
        BLOAD(wfrag + (kk + 2) * 2048 + w * 512 + lane, bA);
        COMPUTE(32768, bB);
        __builtin_amdgcn_s_barrier();
    }
    // tail offset 26 (buf0, bA); no barrier
    COMPUTE(0, bA);

    // ---- epilogue: C/D layout col = lane&15, row = quad*4 + reg ----
    const int n0w = w * 32;
    float bv[2];
    #pragma unroll
    for (int nt = 0; nt < 2; ++nt) bv[nt] = bias[n0w + nt * 16 + lr];

    #pragma unroll
    for (int mt = 0; mt < 8; ++mt) {
        #pragma unroll
        for (int nt = 0; nt < 2; ++nt) {
            #pragma unroll
            for (int r = 0; r < 4; ++r) {
                int grow = tile0 + mt * 16 + quad * 4 + r;
                out[(size_t)grow * COUT + n0w + nt * 16 + lr] =
                    acc[mt][nt][r] + bv[nt];
            }
        }
    }
}

// ---- launch -------------------------------------------------------------

extern "C" void kernel_launch(void* const* d_in, const int* in_sizes, int n_in,
                              void* d_out, int out_size, void* d_ws, size_t ws_size,
                              hipStream_t stream) {
    const float* features = (const float*)d_in[0];   // [N,128] f32
    const float* weight   = (const float*)d_in[1];   // [27,128,128] f32
    const float* bias     = (const float*)d_in[2];   // [128] f32
    const int*   in_idx   = (const int*)d_in[3];     // [27,N] i32
    const int*   out_idx  = (const int*)d_in[4];     // [27,N] i32
    float* out = (float*)d_out;                      // [N,128] f32

    uint8_t* ws = (uint8_t*)d_ws;
    size_t off = 0;
    __hip_bfloat16* feats_bf = (__hip_bfloat16*)(ws + off);       // (N+1)*128*2
    off += (size_t)(NV + 1) * CIN * 2;
    off = (off + 255) & ~(size_t)255;
    uint4* wfrag = (uint4*)(ws + off);                            // 27*128*128*2 B
    off += (size_t)KOFF * CIN * COUT * 2;
    off = (off + 255) & ~(size_t)255;
    int* nbr = (int*)(ws + off);                                  // 27*NSEC*4 (plain order)

    // init nbr to 0xFFFFFFFF (-1 = "no neighbor"; producer clamps to zero row)
    hipMemsetAsync(nbr, 0xFF, (size_t)KOFF * NSEC * 4, stream);

    // fused prep: feature cast + weight fragment-permute + rulebook scatter
    k_prep_all<<<JOB_A_BLOCKS + JOB_B_BLOCKS + JOB_S_BLOCKS, 256, 0, stream>>>(
        features, (uint4*)feats_bf, weight, wfrag,
        (const int4*)in_idx, (const int4*)out_idx, nbr);

    // main gather-GEMM: 512 tiles of 128 rows, 5 waves (4 compute + 1 producer)
    sp_conv_main<<<NV / 128, 320, 0, stream>>>(feats_bf, wfrag, nbr, bias, out);
}

// Round 7
// 164.391 us; speedup vs baseline: 1.5586x; 1.5586x over previous
//
#include <hip/hip_runtime.h>
#include <hip/hip_bf16.h>
#include <stdint.h>

#define NV   65536   // active voxels
#define KOFF 27      // kernel offsets
#define CIN  128
#define COUT 128
#define ZROW 316     // LDS zero-row slot (staged rows occupy 0..315)
#define NROWS 320    // 320 rows * 256 B = 80 KiB LDS

typedef __bf16 bf16x8 __attribute__((ext_vector_type(8)));
typedef float  f32x4  __attribute__((ext_vector_type(4)));

__device__ __forceinline__ void async_copy16(void* lds, const void* g) {
    __builtin_amdgcn_global_load_lds(
        (const __attribute__((address_space(1))) void*)g,
        (__attribute__((address_space(3))) void*)lds,
        16, 0, 0);
}

// ---- prep pass 1: feature cast + weight permute + per-(tile,dx) row range
#define JOB_A_BLOCKS 4097
#define JOB_B_BLOCKS 216    // 27*4*4*2*64 chunks / 256
#define JOB_R_BLOCKS 1728   // 27*65536/4/256

__global__ void k_prep1(const float* __restrict__ f,
                        uint4* __restrict__ fb4,
                        const float* __restrict__ w,
                        uint4* __restrict__ wfrag4,
                        const int4* __restrict__ in4,
                        const int4* __restrict__ out4,
                        int* __restrict__ rmin_a,
                        int* __restrict__ rmax_a) {
    __shared__ int smin[32], smax[32], stile[32];
    const int b = blockIdx.x;
    const int t = threadIdx.x;
    if (b < JOB_A_BLOCKS) {
        int i = b * 256 + t;
        int total8  = (NV + 1) * CIN / 8;
        int nvalid8 = NV * CIN / 8;
        if (i >= total8) return;
        union { uint4 u; __hip_bfloat16 h[8]; } p;
        if (i < nvalid8) {
            const float4* f4 = (const float4*)f;
            float4 a = f4[i * 2];
            float4 c = f4[i * 2 + 1];
            p.h[0] = __float2bfloat16(a.x);
            p.h[1] = __float2bfloat16(a.y);
            p.h[2] = __float2bfloat16(a.z);
            p.h[3] = __float2bfloat16(a.w);
            p.h[4] = __float2bfloat16(c.x);
            p.h[5] = __float2bfloat16(c.y);
            p.h[6] = __float2bfloat16(c.z);
            p.h[7] = __float2bfloat16(c.w);
        } else {
            p.u = make_uint4(0, 0, 0, 0);
        }
        fb4[i] = p.u;
    } else if (b < JOB_A_BLOCKS + JOB_B_BLOCKS) {
        int c    = (b - JOB_A_BLOCKS) * 256 + t;
        int lane = c & 63;
        int nt   = (c >> 6) & 1;
        int ks   = (c >> 7) & 3;
        int wv   = (c >> 9) & 3;
        int k    = c >> 11;
        int cout = wv * 32 + nt * 16 + (lane & 15);
        int cin0 = ks * 32 + (lane >> 4) * 8;
        const float* wk = w + k * 16384;
        union { uint4 u; __hip_bfloat16 h[8]; } p;
        #pragma unroll
        for (int j = 0; j < 8; ++j)
            p.h[j] = __float2bfloat16(wk[(cin0 + j) * 128 + cout]);
        wfrag4[c] = p.u;
    } else {
        // per-(tile, dx-group) row min/max over rulebook entries.
        // out_idx[k] ascending -> a block's 1024 entries span < 32 tiles,
        // so a 32-slot tile hash has no collisions.
        int i = (b - JOB_A_BLOCKS - JOB_B_BLOCKS) * 256 + t;
        int k = i >> 14;            // 16384 int4 per offset
        int g = k / 9;              // dx group
        if (t < 32) { smin[t] = 0x7FFFFFFF; smax[t] = -1; stile[t] = -1; }
        __syncthreads();
        int4 ii = in4[i];
        int4 oo = out4[i];
        int ivals[4] = { ii.x, ii.y, ii.z, ii.w };
        int ovals[4] = { oo.x, oo.y, oo.z, oo.w };
        #pragma unroll
        for (int j = 0; j < 4; ++j) {
            int o = ovals[j];
            if ((unsigned)o < NV) {
                int tl = o >> 7, s = tl & 31;
                stile[s] = tl;                    // benign same-value race
                atomicMin(&smin[s], ivals[j]);
                atomicMax(&smax[s], ivals[j]);
            }
        }
        __syncthreads();
        if (t < 32) {
            int tl = stile[t];
            if (tl >= 0) {
                atomicMin(&rmin_a[tl * 3 + g], smin[t]);
                atomicMax(&rmax_a[tl * 3 + g], smax[t]);
            }
        }
    }
}

// ---- prep pass 2: local-index rulebook (u16), thread-order transposed ----
__global__ void k_prep2(const int4* __restrict__ in4,
                        const int4* __restrict__ out4,
                        const int* __restrict__ rmin_a,
                        unsigned short* __restrict__ lnbr16) {
    int i = blockIdx.x * 256 + threadIdx.x;
    int k = i >> 14;
    int g = k / 9;
    int4 ii = in4[i];
    int4 oo = out4[i];
    int ivals[4] = { ii.x, ii.y, ii.z, ii.w };
    int ovals[4] = { oo.x, oo.y, oo.z, oo.w };
    #pragma unroll
    for (int j = 0; j < 4; ++j) {
        int o = ovals[j];
        if ((unsigned)o < NV) {
            int tl = o >> 7;
            int li = ivals[j] - rmin_a[tl * 3 + g];   // 0..rcount-1 (< 316)
            lnbr16[((size_t)k << 16) + (tl << 7) + (o & 15) * 8 + ((o >> 4) & 7)]
                = (unsigned short)li;
        }
    }
}

// ---- main kernel: stage dx-window ONCE, 9 offsets from LDS --------------
// Per tile: 3 dx-groups. Each group stages a CONTIGUOUS row range
// [rmin, rmin+cnt) (~172 rows, linear copy — no gather!) then runs 9
// offsets of pure {indexed ds_read + MFMA + B/lidx prefetch}. A-fetch per
// tile drops 864 KB -> ~132 KB; 27 per-offset barriers -> 6 syncthreads.
// Invalid/missing neighbors: lnbr=0xFFFF -> min(li,ZROW) -> zero row.
__global__ __launch_bounds__(256, 2)
void sp_conv_main(const __hip_bfloat16* __restrict__ feats,
                  const uint4* __restrict__ wfrag,
                  const unsigned short* __restrict__ lnbr16,
                  const int* __restrict__ rmin_a,
                  const int* __restrict__ rmax_a,
                  const float* __restrict__ bias,
                  float* __restrict__ out) {
    __shared__ unsigned char smem[NROWS * 256];   // 80 KiB -> 2 blocks/CU

    const int t   = threadIdx.x;
    const int bid = blockIdx.x;
    // XCD swizzle: consecutive 64-tile ranges per XCD (512 % 8 == 0)
    const int tile  = (bid & 7) * 64 + (bid >> 3);
    const int tile0 = tile * 128;

    const int w    = t >> 6;
    const int lane = t & 63;
    const int lr   = lane & 15;
    const int quad = lane >> 4;
    const int srow = t >> 4;       // staging row-within-16

    f32x4 acc[8][2] = {};  // 64 VGPRs
    uint4 bX[4][2], bY[4][2];
    uint4 lX, lY;          // 8 u16 local indices each

    const unsigned char* featsB = (const unsigned char*)feats;

    // zero row for missing neighbors (drains at first __syncthreads)
    if (t < 16) *(uint4*)(smem + ZROW * 256 + t * 16) = make_uint4(0, 0, 0, 0);

    auto LLOAD = [&](int k, uint4& l) {
        l = *(const uint4*)(lnbr16 + ((size_t)k << 16) + tile0 + lr * 8);
    };
    auto BLOADf = [&](const uint4* wfk, uint4 (&bf)[4][2]) {
        #pragma unroll
        for (int ks = 0; ks < 4; ++ks)
            #pragma unroll
            for (int nt = 0; nt < 2; ++nt)
                bf[ks][nt] = wfk[ks * 128 + nt * 64];
    };
    auto MFMA16 = [&](bf16x8 (&af)[8], uint4 (&bf)[2]) {
        #pragma unroll
        for (int mt = 0; mt < 8; ++mt)
            #pragma unroll
            for (int nt = 0; nt < 2; ++nt)
                acc[mt][nt] = __builtin_amdgcn_mfma_f32_16x16x32_bf16(
                    af[mt], *(const bf16x8*)&bf[nt], acc[mt][nt], 0, 0, 0);
    };
    // one offset: prefetch lidx(k+1)+B(k+1), compute from LDS with lidx(k)
    auto STEP = [&](int k, uint4& luse, uint4& lload,
                    uint4 (&buse)[4][2], uint4 (&bload)[4][2]) {
        int kn = min(k + 1, KOFF - 1);
        LLOAD(kn, lload);
        BLOADf(wfrag + kn * 2048 + w * 512 + lane, bload);
        const unsigned short* ls = (const unsigned short*)&luse;
        // per-row LDS byte base; chunk XOR lives in bits 4-7 so ks folds
        // in as base ^ (ks<<6)
        unsigned vb[8];
        #pragma unroll
        for (int mt = 0; mt < 8; ++mt) {
            int li = min((int)ls[mt], ZROW);
            vb[mt] = (unsigned)(li * 256 + ((quad << 4) ^ ((li & 15) << 4)));
        }
        #pragma unroll
        for (int ks = 0; ks < 4; ++ks) {
            bf16x8 af[8];
            #pragma unroll
            for (int mt = 0; mt < 8; ++mt)
                af[mt] = *(const bf16x8*)(smem + (vb[mt] ^ (unsigned)(ks << 6)));
            MFMA16(af, buse[ks]);
        }
    };
    // stage contiguous rows [rmin, rmin+cnt): phys chunk c holds global
    // chunk c ^ (row&15) (bank spread for indexed reads)
    auto STAGEG = [&](int g) {
        int rmn = rmin_a[tile * 3 + g];
        int cnt = rmax_a[tile * 3 + g] - rmn + 1;
        cnt = min(cnt, 316);
        const unsigned char* src = featsB + (size_t)rmn * 256 +
                                   (((t & 15) ^ srow) * 16);
        #pragma unroll 1
        for (int j = 0; j < 20; ++j) {
            if (j * 16 >= cnt) break;          // block-uniform
            int row = j * 16 + srow;
            if (row < cnt)
                async_copy16(smem + row * 256 + (t & 15) * 16,
                             src + (size_t)row * 256);
        }
    };
    auto GROUP = [&](int g, uint4& lU, uint4& lV,
                     uint4 (&bU)[4][2], uint4 (&bV)[4][2]) {
        STAGEG(g);
        __syncthreads();        // staging (vmcnt) drained; buffer ready
        const int k0 = g * 9;
        STEP(k0 + 0, lU, lV, bU, bV);
        STEP(k0 + 1, lV, lU, bV, bU);
        STEP(k0 + 2, lU, lV, bU, bV);
        STEP(k0 + 3, lV, lU, bV, bU);
        STEP(k0 + 4, lU, lV, bU, bV);
        STEP(k0 + 5, lV, lU, bV, bU);
        STEP(k0 + 6, lU, lV, bU, bV);
        STEP(k0 + 7, lV, lU, bV, bU);
        STEP(k0 + 8, lU, lV, bU, bV);
        __syncthreads();        // all waves done reading before restage
    };

    // prologue: lidx(0) + B(0)
    LLOAD(0, lX);
    BLOADf(wfrag + w * 512 + lane, bX);

    GROUP(0, lX, lY, bX, bY);   // k 0..8   (ends loading k=9  into lY/bY)
    GROUP(1, lY, lX, bY, bX);   // k 9..17  (ends loading k=18 into lX/bX)
    GROUP(2, lX, lY, bX, bY);   // k 18..26

    // ---- epilogue: C/D layout col = lane&15, row = quad*4 + reg ----
    const int n0w = w * 32;
    float bv[2];
    #pragma unroll
    for (int nt = 0; nt < 2; ++nt) bv[nt] = bias[n0w + nt * 16 + lr];

    #pragma unroll
    for (int mt = 0; mt < 8; ++mt) {
        #pragma unroll
        for (int nt = 0; nt < 2; ++nt) {
            #pragma unroll
            for (int r = 0; r < 4; ++r) {
                int grow = tile0 + mt * 16 + quad * 4 + r;
                out[(size_t)grow * COUT + n0w + nt * 16 + lr] =
                    acc[mt][nt][r] + bv[nt];
            }
        }
    }
}

// ---- launch -------------------------------------------------------------

extern "C" void kernel_launch(void* const* d_in, const int* in_sizes, int n_in,
                              void* d_out, int out_size, void* d_ws, size_t ws_size,
                              hipStream_t stream) {
    const float* features = (const float*)d_in[0];   // [N,128] f32
    const float* weight   = (const float*)d_in[1];   // [27,128,128] f32
    const float* bias     = (const float*)d_in[2];   // [128] f32
    const int*   in_idx   = (const int*)d_in[3];     // [27,N] i32
    const int*   out_idx  = (const int*)d_in[4];     // [27,N] i32
    float* out = (float*)d_out;                      // [N,128] f32

    uint8_t* ws = (uint8_t*)d_ws;
    size_t off = 0;
    __hip_bfloat16* feats_bf = (__hip_bfloat16*)(ws + off);       // (N+1)*256 B
    off += (size_t)(NV + 1) * CIN * 2;
    off = (off + 255) & ~(size_t)255;
    uint4* wfrag = (uint4*)(ws + off);                            // 884736 B
    off += (size_t)KOFF * CIN * COUT * 2;
    off = (off + 255) & ~(size_t)255;
    unsigned short* lnbr16 = (unsigned short*)(ws + off);         // 27*65536*2 B
    off += (size_t)KOFF * NV * 2;
    off = (off + 255) & ~(size_t)255;
    int* rmin_a = (int*)(ws + off);                               // 512*3*4 B
    off += 512 * 3 * 4;
    off = (off + 255) & ~(size_t)255;
    int* rmax_a = (int*)(ws + off);                               // 512*3*4 B

    // sentinels: lnbr=0xFFFF (missing -> ZROW); rmin large; rmax 0
    hipMemsetAsync(lnbr16, 0xFF, (size_t)KOFF * NV * 2, stream);
    hipMemsetAsync(rmin_a, 0x7F, 512 * 3 * 4, stream);
    hipMemsetAsync(rmax_a, 0x00, 512 * 3 * 4, stream);

    k_prep1<<<JOB_A_BLOCKS + JOB_B_BLOCKS + JOB_R_BLOCKS, 256, 0, stream>>>(
        features, (uint4*)feats_bf, weight, wfrag,
        (const int4*)in_idx, (const int4*)out_idx, rmin_a, rmax_a);

    k_prep2<<<JOB_R_BLOCKS, 256, 0, stream>>>(
        (const int4*)in_idx, (const int4*)out_idx, rmin_a, lnbr16);

    sp_conv_main<<<NV / 128, 256, 0, stream>>>(
        feats_bf, wfrag, lnbr16, rmin_a, rmax_a, bias, out);
}

// Round 8
// 160.274 us; speedup vs baseline: 1.5986x; 1.0257x over previous
//
#include <hip/hip_runtime.h>
#include <hip/hip_bf16.h>
#include <stdint.h>

#define NV   65536   // active voxels
#define KOFF 27      // kernel offsets
#define CIN  128
#define COUT 128
#define NSEC (NV + 128)   // nbr_t per-offset stride (16B-aligned, holds dummy slot)

typedef __bf16 bf16x8 __attribute__((ext_vector_type(8)));
typedef float  f32x16 __attribute__((ext_vector_type(16)));

__device__ __forceinline__ void async_copy16(void* lds, const void* g) {
    __builtin_amdgcn_global_load_lds(
        (const __attribute__((address_space(1))) void*)g,
        (__attribute__((address_space(3))) void*)lds,
        16, 0, 0);
}

// ---- fused prep kernel --------------------------------------------------
// Job B: weight -> fragment-major bf16 for mfma_f32_32x32x16_bf16:
//   chunk c = k*2048 + wc*1024 + nb*512 + ks*64 + lane holds 8 bf16 =
//   B[cin = ks*16 + (lane>>5)*8 + j][cout = wc*64 + nb*32 + (lane&31)]
// Job S: thread-order-transposed rulebook (R4-proven):
//   nbr_t[k][tile*128 + (o&15)*8 + ((o>>4)&7)] = in-row of out-row o
#define JOB_A_BLOCKS 4097
#define JOB_B_BLOCKS 216    // 27*2048 chunks / 256
#define JOB_S_BLOCKS 1728   // 27*65536/4/256

__global__ void k_prep_all(const float* __restrict__ f,
                           uint4* __restrict__ fb4,
                           const float* __restrict__ w,
                           uint4* __restrict__ wfrag4,
                           const int4* __restrict__ in4,
                           const int4* __restrict__ out4,
                           int* __restrict__ nbr) {
    const int b = blockIdx.x;
    const int t = threadIdx.x;
    if (b < JOB_A_BLOCKS) {
        int i = b * 256 + t;
        int total8  = (NV + 1) * CIN / 8;
        int nvalid8 = NV * CIN / 8;
        if (i >= total8) return;
        union { uint4 u; __hip_bfloat16 h[8]; } p;
        if (i < nvalid8) {
            const float4* f4 = (const float4*)f;
            float4 a = f4[i * 2];
            float4 c = f4[i * 2 + 1];
            p.h[0] = __float2bfloat16(a.x);
            p.h[1] = __float2bfloat16(a.y);
            p.h[2] = __float2bfloat16(a.z);
            p.h[3] = __float2bfloat16(a.w);
            p.h[4] = __float2bfloat16(c.x);
            p.h[5] = __float2bfloat16(c.y);
            p.h[6] = __float2bfloat16(c.z);
            p.h[7] = __float2bfloat16(c.w);
        } else {
            p.u = make_uint4(0, 0, 0, 0);
        }
        fb4[i] = p.u;
    } else if (b < JOB_A_BLOCKS + JOB_B_BLOCKS) {
        int c    = (b - JOB_A_BLOCKS) * 256 + t;   // chunk index
        int lane = c & 63;
        int ks   = (c >> 6) & 7;
        int nb   = (c >> 9) & 1;
        int wc   = (c >> 10) & 1;
        int k    = c >> 11;
        int cout = wc * 64 + nb * 32 + (lane & 31);
        int cin0 = ks * 16 + (lane >> 5) * 8;
        const float* wk = w + k * 16384;
        union { uint4 u; __hip_bfloat16 h[8]; } p;
        #pragma unroll
        for (int j = 0; j < 8; ++j)
            p.h[j] = __float2bfloat16(wk[(cin0 + j) * 128 + cout]);
        wfrag4[c] = p.u;
    } else {
        int i = (b - JOB_A_BLOCKS - JOB_B_BLOCKS) * 256 + t;
        int k = i >> 14;
        int4 ii = in4[i];
        int4 oo = out4[i];
        int* nb = nbr + (size_t)k * NSEC;
        auto POS = [](int o) {
            return (o >> 7) * 128 + (o & 15) * 8 + ((o >> 4) & 7);
        };
        nb[POS(oo.x)] = ii.x;
        nb[POS(oo.y)] = ii.y;
        nb[POS(oo.z)] = ii.z;
        nb[POS(oo.w)] = ii.w;
    }
}

// ---- main gather-GEMM kernel -------------------------------------------
// 32x32x16 MFMA, wave grid 2x2, each wave 64 rows x 64 cols.
// Per-CU per-offset resource rebalance vs R4 (which was ~5100 cyc):
//   MFMA issue 2483 -> 2066 cyc/SIMD (32x32 ceiling 2495 vs 2075 TF)
//   LDS reads  256 KB -> 128 KB (~1540 cyc at 85 B/cyc)
//   B from L1/L2 regs, bcur[8][2] refilled IN PLACE right after each
//   frag's last use (full-offset latency cover, no bnext, no sched pins).
// Staging/nbr/vmcnt/barrier structure = R4 (proven, 0 bank conflicts).
__global__ __launch_bounds__(256, 2)
void sp_conv_main(const __hip_bfloat16* __restrict__ feats,
                  const uint4* __restrict__ wfrag,
                  const int* __restrict__ nbrt,
                  const float* __restrict__ bias,
                  float* __restrict__ out) {
    __shared__ unsigned char smem[65536];   // two 32 KB A buffers

    const int t   = threadIdx.x;
    const int bid = blockIdx.x;
    // XCD swizzle: consecutive 64-tile ranges per XCD (512 % 8 == 0)
    const int tile0 = ((bid & 7) * 64 + (bid >> 3)) * 128;

    const int w    = t >> 6;
    const int lane = t & 63;
    const int wr   = w >> 1;        // rows [wr*64, +64)
    const int wc   = w & 1;         // cols [wc*64, +64)
    const int l31  = lane & 31;
    const int part = lane >> 5;     // k-half within fragment
    const int x15  = lane & 15;

    // staging map (R4): LDS slot (row=i*16+srow, phys chunk t&15) holds
    // global chunk (t&15)^(row&15)
    const int srow  = t >> 4;
    const int sbyte = ((t & 15) ^ srow) * 16;

    // A-read bases: row = wr*64 + mr*32 + l31; row&15 == x15
    const int rowb0 = (wr * 64 + l31) * 256;   // mr=0
    const int rowb1 = rowb0 + 8192;            // mr=1 (+32 rows)

    f32x16 acc[2][2] = {};  // 64 VGPRs
    uint4  bcur[8][2];      // 64 VGPRs, in-place rotated

    const unsigned char* featsB = (const unsigned char*)feats;
    int arows[8];

    auto NLOAD = [&](int k) {   // 2 x int4: rows i*16+srow, i=0..7
        const int4* np = (const int4*)(nbrt + (size_t)k * NSEC + tile0 + srow * 8);
        int4 a0 = np[0];
        int4 a1 = np[1];
        arows[0] = a0.x; arows[1] = a0.y; arows[2] = a0.z; arows[3] = a0.w;
        arows[4] = a1.x; arows[5] = a1.y; arows[6] = a1.z; arows[7] = a1.w;
    };
    auto STAGE = [&](int sb) {
        #pragma unroll
        for (int i = 0; i < 8; ++i) {
            unsigned ar = min((unsigned)arows[i], (unsigned)NV);
            async_copy16(smem + sb + i * 4096 + t * 16,
                         featsB + (size_t)ar * 256 + sbyte);
        }
    };

    // ---- prologue: nbr(0) -> stage A0 -> nbr(1), B(0) ----
    NLOAD(0);
    STAGE(0);
    __builtin_amdgcn_sched_barrier(0);   // staging ops oldest in vm queue
    NLOAD(1);
    {
        const uint4* wf0 = wfrag + wc * 1024 + lane;
        #pragma unroll
        for (int ks = 0; ks < 8; ++ks) {
            bcur[ks][0] = wf0[ks * 64];
            bcur[ks][1] = wf0[ks * 64 + 512];
        }
    }
    // 18 younger vm ops (2 nbr + 16 B) -> staging A0 guaranteed complete
    asm volatile("s_waitcnt vmcnt(18)" ::: "memory");
    __builtin_amdgcn_s_barrier();
    __builtin_amdgcn_sched_barrier(0);

    // ---- one offset ----
    auto ITER = [&](int k, int rb) {
        STAGE(rb ^ 32768);                       // A(k+1) -> other buffer
        __builtin_amdgcn_sched_barrier(0);       // keep staging oldest
        NLOAD(min(k + 2, KOFF - 1));             // rows for offset k+2
        const uint4* wfn = wfrag + (k + 1) * 2048 + wc * 1024 + lane;
        #pragma unroll
        for (int ks = 0; ks < 8; ++ks) {
            bf16x8 af0 = *(const bf16x8*)(smem + rb + rowb0 +
                                          (((ks * 2 + part) ^ x15) << 4));
            bf16x8 af1 = *(const bf16x8*)(smem + rb + rowb1 +
                                          (((ks * 2 + part) ^ x15) << 4));
            acc[0][0] = __builtin_amdgcn_mfma_f32_32x32x16_bf16(
                af0, *(const bf16x8*)&bcur[ks][0], acc[0][0], 0, 0, 0);
            acc[0][1] = __builtin_amdgcn_mfma_f32_32x32x16_bf16(
                af0, *(const bf16x8*)&bcur[ks][1], acc[0][1], 0, 0, 0);
            acc[1][0] = __builtin_amdgcn_mfma_f32_32x32x16_bf16(
                af1, *(const bf16x8*)&bcur[ks][0], acc[1][0], 0, 0, 0);
            acc[1][1] = __builtin_amdgcn_mfma_f32_32x32x16_bf16(
                af1, *(const bf16x8*)&bcur[ks][1], acc[1][1], 0, 0, 0);
            // refill this ks slot with B(k+1) — last use was just above,
            // next use is a full offset away (~1000 cyc latency cover)
            bcur[ks][0] = wfn[ks * 64];
            bcur[ks][1] = wfn[ks * 64 + 512];
        }
        // own 8 staging loads complete; 18 nbr/B stay in flight (T4)
        asm volatile("s_waitcnt vmcnt(18)" ::: "memory");
        __builtin_amdgcn_s_barrier();
        __builtin_amdgcn_sched_barrier(0);
    };

    #pragma unroll 1
    for (int kk = 0; kk < KOFF - 1; kk += 2) {
        ITER(kk,     0);       // even k: read buf0, stage buf1
        ITER(kk + 1, 32768);   // odd  k: read buf1, stage buf0
    }

    // ---- tail k=26: buf0, bcur already holds B(26); no loads/barriers ----
    #pragma unroll
    for (int ks = 0; ks < 8; ++ks) {
        bf16x8 af0 = *(const bf16x8*)(smem + rowb0 + (((ks * 2 + part) ^ x15) << 4));
        bf16x8 af1 = *(const bf16x8*)(smem + rowb1 + (((ks * 2 + part) ^ x15) << 4));
        acc[0][0] = __builtin_amdgcn_mfma_f32_32x32x16_bf16(
            af0, *(const bf16x8*)&bcur[ks][0], acc[0][0], 0, 0, 0);
        acc[0][1] = __builtin_amdgcn_mfma_f32_32x32x16_bf16(
            af0, *(const bf16x8*)&bcur[ks][1], acc[0][1], 0, 0, 0);
        acc[1][0] = __builtin_amdgcn_mfma_f32_32x32x16_bf16(
            af1, *(const bf16x8*)&bcur[ks][0], acc[1][0], 0, 0, 0);
        acc[1][1] = __builtin_amdgcn_mfma_f32_32x32x16_bf16(
            af1, *(const bf16x8*)&bcur[ks][1], acc[1][1], 0, 0, 0);
    }

    // ---- epilogue: 32x32 C/D map: col=lane&31, row=(reg&3)+8*(reg>>2)+4*part
    float bv[2];
    #pragma unroll
    for (int nb = 0; nb < 2; ++nb) bv[nb] = bias[wc * 64 + nb * 32 + l31];

    #pragma unroll
    for (int mr = 0; mr < 2; ++mr) {
        #pragma unroll
        for (int nb = 0; nb < 2; ++nb) {
            #pragma unroll
            for (int r = 0; r < 16; ++r) {
                int grow = tile0 + wr * 64 + mr * 32 +
                           (r & 3) + 8 * (r >> 2) + 4 * part;
                int gcol = wc * 64 + nb * 32 + l31;
                out[(size_t)grow * COUT + gcol] = acc[mr][nb][r] + bv[nb];
            }
        }
    }
}

// ---- launch -------------------------------------------------------------

extern "C" void kernel_launch(void* const* d_in, const int* in_sizes, int n_in,
                              void* d_out, int out_size, void* d_ws, size_t ws_size,
                              hipStream_t stream) {
    const float* features = (const float*)d_in[0];   // [N,128] f32
    const float* weight   = (const float*)d_in[1];   // [27,128,128] f32
    const float* bias     = (const float*)d_in[2];   // [128] f32
    const int*   in_idx   = (const int*)d_in[3];     // [27,N] i32
    const int*   out_idx  = (const int*)d_in[4];     // [27,N] i32
    float* out = (float*)d_out;                      // [N,128] f32

    uint8_t* ws = (uint8_t*)d_ws;
    size_t off = 0;
    __hip_bfloat16* feats_bf = (__hip_bfloat16*)(ws + off);       // (N+1)*256 B
    off += (size_t)(NV + 1) * CIN * 2;
    off = (off + 255) & ~(size_t)255;
    uint4* wfrag = (uint4*)(ws + off);                            // 27*2048*16 B
    off += (size_t)KOFF * CIN * COUT * 2;
    off = (off + 255) & ~(size_t)255;
    int* nbr = (int*)(ws + off);                                  // 27*NSEC*4 (transposed)

    // init nbr_t to 0xFFFFFFFF (-1 = "no neighbor"; main clamps to zero row)
    hipMemsetAsync(nbr, 0xFF, (size_t)KOFF * NSEC * 4, stream);

    // fused prep: feature cast + weight fragment-permute + rulebook scatter
    k_prep_all<<<JOB_A_BLOCKS + JOB_B_BLOCKS + JOB_S_BLOCKS, 256, 0, stream>>>(
        features, (uint4*)feats_bf, weight, wfrag,
        (const int4*)in_idx, (const int4*)out_idx, nbr);

    // main gather-GEMM: 512 tiles of 128 rows
    sp_conv_main<<<NV / 128, 256, 0, stream>>>(feats_bf, wfrag, nbr, bias, out);
}